// Round 7
// baseline (660.708 us; speedup 1.0000x reference)
//
#include <hip/hip_runtime.h>
#include <hip/hip_bf16.h>
#include <hip/hip_cooperative_groups.h>
#include <stdint.h>

namespace cg = cooperative_groups;

// Problem constants (from reference setup_inputs)
constexpr int cB  = 8;
constexpr int cC  = 256;
constexpr int cHW = 128 * 128;   // 16384
constexpr int cN  = 100;
constexpr int cT  = 6;
constexpr int NPAD = 112;        // cN padded to multiple of 16
constexpr int WPB = cHW / 32;    // 512 bit-words per (b,n) row
constexpr int KSLICES = 32;      // k-slices per (b, c-tile)
constexpr int PXS = cHW / KSLICES;   // 512 px per wave
constexpr int NWIN = PXS / 32;       // 16 windows of 32 px
constexpr int NGRP = NWIN / 4;       // 4 groups of 4 windows
constexpr int NBLK = cB * 16 * (KSLICES / 4);  // 1024 blocks (4 ks per block)

typedef __attribute__((ext_vector_type(8))) short short8;
typedef __attribute__((ext_vector_type(4))) float floatx4;

// RNE fp32 pair -> packed bf16x2 (compiler emits v_cvt_pk_bf16_f32 on gfx950)
__device__ __forceinline__ unsigned pack2(float a, float b) {
    const __hip_bfloat16 ha = __float2bfloat16(a);
    const __hip_bfloat16 hb = __float2bfloat16(b);
    return (unsigned)__builtin_bit_cast(unsigned short, ha)
         | ((unsigned)__builtin_bit_cast(unsigned short, hb) << 16);
}

__device__ __forceinline__ float wred(float v) {
    #pragma unroll
    for (int off = 32; off > 0; off >>= 1) v += __shfl_xor(v, off, 64);
    return v;
}

// ===========================================================================
// Fused cooperative kernel: prep -> pool -> finalize -> loss with grid syncs.
// grid = 1024 blocks x 256 threads (4 blocks/CU, 16 waves/CU co-resident).
// ===========================================================================
__global__ __launch_bounds__(256, 4)
void fused_kernel(const float* __restrict__ vf, const float* __restrict__ masks,
                  const float* __restrict__ text, const int* __restrict__ labels,
                  const float* __restrict__ temp,
                  unsigned* __restrict__ bits, unsigned* __restrict__ msum,
                  float* __restrict__ part, float* __restrict__ bpart,
                  float* __restrict__ out)
{
    cg::grid_group grid = cg::this_grid();
    __shared__ float red[4][28][64];     // pool-phase reduce (28 KB)
    __shared__ int   ips[4];
    __shared__ float lce[4], lcnt[4];

    const int tid  = threadIdx.x;
    const int lane = tid & 63;
    const int widx = tid >> 6;

    // ---------------- Phase A: mask binarize + bit-pack + msum --------------
    // Bit order within a 32-px word: px offset o = lambda*4+c <-> bit c*8+lambda
    {
        const int unit = blockIdx.x;
        if (unit < cB * NPAD) {
            const int b = unit / NPAD;
            const int n = unit % NPAD;
            unsigned* dst = bits + ((size_t)b * NPAD + n) * WPB;
            if (n >= cN) {
                *(uint2*)(dst + tid * 2) = make_uint2(0u, 0u);
            } else {
                const float* src = masks + ((size_t)b * cN + n) * cHW + widx * 4096;
                unsigned* wdst = dst + widx * 128;
                int pc = 0;
                #pragma unroll
                for (int r = 0; r < 16; ++r) {
                    const floatx4 v = *(const floatx4*)(src + r * 256 + lane * 4);
                    const bool b0 = v.x > 0.5f, b1 = v.y > 0.5f,
                               b2 = v.z > 0.5f, b3 = v.w > 0.5f;
                    const unsigned long long B0 = __ballot(b0), B1 = __ballot(b1),
                                             B2 = __ballot(b2), B3 = __ballot(b3);
                    pc += (int)b0 + (int)b1 + (int)b2 + (int)b3;
                    if (lane < 8) {
                        const int sh = lane * 8;
                        const unsigned word =
                              (unsigned)((B0 >> sh) & 0xFFull)
                            | ((unsigned)((B1 >> sh) & 0xFFull) << 8)
                            | ((unsigned)((B2 >> sh) & 0xFFull) << 16)
                            | ((unsigned)((B3 >> sh) & 0xFFull) << 24);
                        wdst[r * 8 + lane] = word;
                    }
                }
                #pragma unroll
                for (int off = 32; off > 0; off >>= 1) pc += __shfl_xor(pc, off, 64);
                if (lane == 0) ips[widx] = pc;
                __syncthreads();
                if (tid == 0)
                    msum[b * cN + n] = (unsigned)(ips[0] + ips[1] + ips[2] + ips[3]);
            }
        }
    }
    __threadfence();
    grid.sync();

    // ---------------- Phase B: pooling GEMM (MFMA, no LDS staging) ----------
    {
        const int bid  = blockIdx.x;
        const int b    = bid >> 7;
        const int ct   = (bid >> 3) & 15;
        const int kg   = bid & 7;
        const int ks   = kg * 4 + widx;
        const int l15  = lane & 15;
        const int lk   = lane >> 4;
        const int lk2  = lk * 2;
        const int p0   = ks * PXS;

        const float* vrow = vf + ((size_t)(b * cC + ct * 16 + l15)) * cHW + p0 + lk * 8;
        const unsigned* brow = bits + ((size_t)b * NPAD + l15) * WPB + (p0 >> 5);

        floatx4 acc[7];
        #pragma unroll
        for (int mt = 0; mt < 7; ++mt) acc[mt] = (floatx4){0.f, 0.f, 0.f, 0.f};

        // B prefetch: depth 4 windows, 2 float4 each
        floatx4 vr[4][2];
        #pragma unroll
        for (int u = 0; u < 4; ++u) {
            vr[u][0] = *(const floatx4*)(vrow + u * 32);
            vr[u][1] = *(const floatx4*)(vrow + u * 32 + 4);
        }

        #pragma unroll
        for (int g = 0; g < NGRP; ++g) {
            uint4 bw[7];
            #pragma unroll
            for (int mt = 0; mt < 7; ++mt)
                bw[mt] = *(const uint4*)(brow + (size_t)mt * 16 * WPB + g * 4);
            #pragma unroll
            for (int u = 0; u < 4; ++u) {
                const int w = g * 4 + u;
                // ---- B fragment: 8 fp32 -> 8 bf16 (RNE)
                union { short8 s8; uint4 u4; } bq;
                bq.u4.x = pack2(vr[u][0].x, vr[u][0].y);
                bq.u4.y = pack2(vr[u][0].z, vr[u][0].w);
                bq.u4.z = pack2(vr[u][1].x, vr[u][1].y);
                bq.u4.w = pack2(vr[u][1].z, vr[u][1].w);
                // ---- issue B loads for window w+4
                if (g < NGRP - 1) {
                    vr[u][0] = *(const floatx4*)(vrow + (w + 4) * 32);
                    vr[u][1] = *(const floatx4*)(vrow + (w + 4) * 32 + 4);
                }
                // ---- A expand + MFMA per n-tile
                #pragma unroll
                for (int mt = 0; mt < 7; ++mt) {
                    const unsigned word = (u == 0) ? bw[mt].x : (u == 1) ? bw[mt].y
                                        : (u == 2) ? bw[mt].z : bw[mt].w;
                    // frag element j <-> bit (j&3)*8 + lk*2 + (j>>2)
                    const unsigned te = (word >> lk2) & 0x01010101u;
                    const unsigned to = (word >> (lk2 + 1)) & 0x01010101u;
                    union { short8 s8; uint4 u4; } aq;
                    aq.u4.x = __umul24(__builtin_amdgcn_perm(0u, te, 0x04010400u), 0x3F80u);
                    aq.u4.y = __umul24(__builtin_amdgcn_perm(0u, te, 0x04030402u), 0x3F80u);
                    aq.u4.z = __umul24(__builtin_amdgcn_perm(0u, to, 0x04010400u), 0x3F80u);
                    aq.u4.w = __umul24(__builtin_amdgcn_perm(0u, to, 0x04030402u), 0x3F80u);
                    acc[mt] = __builtin_amdgcn_mfma_f32_16x16x32_bf16(aq.s8, bq.s8, acc[mt], 0, 0, 0);
                }
            }
        }

        // ---- LDS reduce across the 4 waves (4 k-slices of same (b,ct))
        #pragma unroll
        for (int mt = 0; mt < 7; ++mt)
            #pragma unroll
            for (int i = 0; i < 4; ++i)
                red[widx][mt * 4 + i][lane] = acc[mt][i];
        __syncthreads();

        float s[7];
        #pragma unroll
        for (int mt = 0; mt < 7; ++mt) {
            const int e = mt * 4 + widx;
            s[mt] = red[0][e][lane] + red[1][e][lane] + red[2][e][lane] + red[3][e][lane];
        }
        float* dst = part + (size_t)bid * (cN * 16);
        #pragma unroll
        for (int mt = 0; mt < 7; ++mt) {
            const int n = mt * 16 + (lane >> 4) * 4 + widx;
            if (n < cN) dst[n * 16 + l15] = s[mt];
        }
    }
    __threadfence();
    grid.sync();

    // ---------------- Phase C: finalize (200 blocks) ------------------------
    if (blockIdx.x < cB * cN / 4) {
        const int row = blockIdx.x * 4 + widx;
        const int b = row / cN, n = row % cN;
        const int ct  = lane >> 2;
        const int col = (lane & 3) * 4;

        floatx4 p = (floatx4){0.f, 0.f, 0.f, 0.f};
        const float* src = part + ((size_t)(b * 16 + ct) * 8) * (cN * 16) + n * 16 + col;
        #pragma unroll
        for (int kg = 0; kg < 8; ++kg)
            p += *(const floatx4*)(src + (size_t)kg * (cN * 16));

        const float m   = (float)msum[row];
        const float inv = 1.0f / fmaxf(m, 1.0f);
        p.x *= inv; p.y *= inv; p.z *= inv; p.w *= inv;

        const int c_global = ct * 16 + col;
        float psq = p.x * p.x + p.y * p.y + p.z * p.z + p.w * p.w;
        float dot[cT], tsq[cT];
        #pragma unroll
        for (int t = 0; t < cT; ++t) {
            const floatx4 x = *(const floatx4*)(text + (size_t)t * cC + c_global);
            dot[t] = p.x * x.x + p.y * x.y + p.z * x.z + p.w * x.w;
            tsq[t] = x.x * x.x + x.y * x.y + x.z * x.z + x.w * x.w;
        }
        psq = wred(psq);
        #pragma unroll
        for (int t = 0; t < cT; ++t) { dot[t] = wred(dot[t]); tsq[t] = wred(tsq[t]); }

        if (lane == 0) {
            const float tempv = fabsf(temp[0]);
            const float pn = fmaxf(sqrtf(psq), 1e-12f);
            float sims[cT], mx = -1e30f;
            #pragma unroll
            for (int t = 0; t < cT; ++t) {
                sims[t] = dot[t] / (pn * fmaxf(sqrtf(tsq[t]), 1e-12f)) / tempv;
                mx = fmaxf(mx, sims[t]);
            }
            float se = 0.f;
            #pragma unroll
            for (int t = 0; t < cT; ++t) se += expf(sims[t] - mx);
            const float lse = logf(se);

            const int lab = labels[row];
            const int tgt = min(max(lab - 1, 0), cT - 1);
            const float ce = -(sims[tgt] - mx - lse);
            const bool valid = (lab >= 1) && (lab <= cT) && (m >= 1.0f);
            lce[widx]  = valid ? ce : 0.f;
            lcnt[widx] = valid ? 1.f : 0.f;
        }
        __syncthreads();
        if (tid == 0) {
            bpart[blockIdx.x * 2]     = lce[0] + lce[1] + lce[2] + lce[3];
            bpart[blockIdx.x * 2 + 1] = lcnt[0] + lcnt[1] + lcnt[2] + lcnt[3];
        }
    }
    __threadfence();
    grid.sync();

    // ---------------- Phase D: final loss (block 0) -------------------------
    if (blockIdx.x == 0) {
        float ce = 0.f, cnt = 0.f;
        if (tid < 200) { ce = bpart[tid * 2]; cnt = bpart[tid * 2 + 1]; }
        ce = wred(ce); cnt = wred(cnt);
        if (lane == 0) { lce[widx] = ce; lcnt[widx] = cnt; }
        __syncthreads();
        if (tid == 0) {
            const float s = lce[0] + lce[1] + lce[2] + lce[3];
            const float c = lcnt[0] + lcnt[1] + lcnt[2] + lcnt[3];
            out[0] = (c > 0.f) ? s / fmaxf(c, 1.f) : 0.f;
        }
    }
}

// ===========================================================================
// Fallback path (separate kernels) — used if coop launch is unavailable.
// ===========================================================================
__global__ __launch_bounds__(256)
void mask_prep_kernel(const float* __restrict__ masks,
                      unsigned* __restrict__ bits, unsigned* __restrict__ msum)
{
    const int t = threadIdx.x, lane = t & 63, w = t >> 6;
    const int b = blockIdx.x / NPAD;
    const int n = blockIdx.x % NPAD;
    unsigned* dst = bits + ((size_t)b * NPAD + n) * WPB;
    if (n >= cN) { *(uint2*)(dst + t * 2) = make_uint2(0u, 0u); return; }
    const float* src = masks + ((size_t)b * cN + n) * cHW + w * 4096;
    unsigned* wdst = dst + w * 128;
    int pc = 0;
    #pragma unroll
    for (int r = 0; r < 16; ++r) {
        const floatx4 v = *(const floatx4*)(src + r * 256 + lane * 4);
        const bool b0 = v.x > 0.5f, b1 = v.y > 0.5f, b2 = v.z > 0.5f, b3 = v.w > 0.5f;
        const unsigned long long B0 = __ballot(b0), B1 = __ballot(b1),
                                 B2 = __ballot(b2), B3 = __ballot(b3);
        pc += (int)b0 + (int)b1 + (int)b2 + (int)b3;
        if (lane < 8) {
            const int sh = lane * 8;
            const unsigned word =
                  (unsigned)((B0 >> sh) & 0xFFull)
                | ((unsigned)((B1 >> sh) & 0xFFull) << 8)
                | ((unsigned)((B2 >> sh) & 0xFFull) << 16)
                | ((unsigned)((B3 >> sh) & 0xFFull) << 24);
            wdst[r * 8 + lane] = word;
        }
    }
    #pragma unroll
    for (int off = 32; off > 0; off >>= 1) pc += __shfl_xor(pc, off, 64);
    __shared__ int ps[4];
    if (lane == 0) ps[w] = pc;
    __syncthreads();
    if (t == 0) msum[b * cN + n] = (unsigned)(ps[0] + ps[1] + ps[2] + ps[3]);
}

__global__ __launch_bounds__(256)
void pool_kernel(const float* __restrict__ vf, const unsigned* __restrict__ bits,
                 float* __restrict__ part)
{
    __shared__ float red[4][28][64];
    const int tid  = threadIdx.x;
    const int lane = tid & 63;
    const int widx = tid >> 6;
    const int bid  = blockIdx.x;
    const int b    = bid >> 7;
    const int ct   = (bid >> 3) & 15;
    const int kg   = bid & 7;
    const int ks   = kg * 4 + widx;
    const int l15  = lane & 15;
    const int lk   = lane >> 4;
    const int lk2  = lk * 2;
    const int p0   = ks * PXS;

    const float* vrow = vf + ((size_t)(b * cC + ct * 16 + l15)) * cHW + p0 + lk * 8;
    const unsigned* brow = bits + ((size_t)b * NPAD + l15) * WPB + (p0 >> 5);

    floatx4 acc[7];
    #pragma unroll
    for (int mt = 0; mt < 7; ++mt) acc[mt] = (floatx4){0.f, 0.f, 0.f, 0.f};
    floatx4 vr[4][2];
    #pragma unroll
    for (int u = 0; u < 4; ++u) {
        vr[u][0] = *(const floatx4*)(vrow + u * 32);
        vr[u][1] = *(const floatx4*)(vrow + u * 32 + 4);
    }
    #pragma unroll
    for (int g = 0; g < NGRP; ++g) {
        uint4 bw[7];
        #pragma unroll
        for (int mt = 0; mt < 7; ++mt)
            bw[mt] = *(const uint4*)(brow + (size_t)mt * 16 * WPB + g * 4);
        #pragma unroll
        for (int u = 0; u < 4; ++u) {
            const int w = g * 4 + u;
            union { short8 s8; uint4 u4; } bq;
            bq.u4.x = pack2(vr[u][0].x, vr[u][0].y);
            bq.u4.y = pack2(vr[u][0].z, vr[u][0].w);
            bq.u4.z = pack2(vr[u][1].x, vr[u][1].y);
            bq.u4.w = pack2(vr[u][1].z, vr[u][1].w);
            if (g < NGRP - 1) {
                vr[u][0] = *(const floatx4*)(vrow + (w + 4) * 32);
                vr[u][1] = *(const floatx4*)(vrow + (w + 4) * 32 + 4);
            }
            #pragma unroll
            for (int mt = 0; mt < 7; ++mt) {
                const unsigned word = (u == 0) ? bw[mt].x : (u == 1) ? bw[mt].y
                                    : (u == 2) ? bw[mt].z : bw[mt].w;
                const unsigned te = (word >> lk2) & 0x01010101u;
                const unsigned to = (word >> (lk2 + 1)) & 0x01010101u;
                union { short8 s8; uint4 u4; } aq;
                aq.u4.x = __umul24(__builtin_amdgcn_perm(0u, te, 0x04010400u), 0x3F80u);
                aq.u4.y = __umul24(__builtin_amdgcn_perm(0u, te, 0x04030402u), 0x3F80u);
                aq.u4.z = __umul24(__builtin_amdgcn_perm(0u, to, 0x04010400u), 0x3F80u);
                aq.u4.w = __umul24(__builtin_amdgcn_perm(0u, to, 0x04030402u), 0x3F80u);
                acc[mt] = __builtin_amdgcn_mfma_f32_16x16x32_bf16(aq.s8, bq.s8, acc[mt], 0, 0, 0);
            }
        }
    }
    #pragma unroll
    for (int mt = 0; mt < 7; ++mt)
        #pragma unroll
        for (int i = 0; i < 4; ++i)
            red[widx][mt * 4 + i][lane] = acc[mt][i];
    __syncthreads();
    float s[7];
    #pragma unroll
    for (int mt = 0; mt < 7; ++mt) {
        const int e = mt * 4 + widx;
        s[mt] = red[0][e][lane] + red[1][e][lane] + red[2][e][lane] + red[3][e][lane];
    }
    float* dst = part + (size_t)bid * (cN * 16);
    #pragma unroll
    for (int mt = 0; mt < 7; ++mt) {
        const int n = mt * 16 + (lane >> 4) * 4 + widx;
        if (n < cN) dst[n * 16 + l15] = s[mt];
    }
}

__global__ __launch_bounds__(256)
void finalize_kernel(const float* __restrict__ pp, const unsigned* __restrict__ msum,
                     const float* __restrict__ text, const int* __restrict__ labels,
                     const float* __restrict__ temp, float* __restrict__ bpart)
{
    const int lane = threadIdx.x & 63;
    const int wv   = threadIdx.x >> 6;
    const int row  = blockIdx.x * 4 + wv;
    const int b = row / cN, n = row % cN;
    const int ct  = lane >> 2;
    const int col = (lane & 3) * 4;

    floatx4 p = (floatx4){0.f, 0.f, 0.f, 0.f};
    const float* src = pp + ((size_t)(b * 16 + ct) * 8) * (cN * 16) + n * 16 + col;
    #pragma unroll
    for (int kg = 0; kg < 8; ++kg)
        p += *(const floatx4*)(src + (size_t)kg * (cN * 16));

    const float m   = (float)msum[row];
    const float inv = 1.0f / fmaxf(m, 1.0f);
    p.x *= inv; p.y *= inv; p.z *= inv; p.w *= inv;

    const int c_global = ct * 16 + col;
    float psq = p.x * p.x + p.y * p.y + p.z * p.z + p.w * p.w;
    float dot[cT], tsq[cT];
    #pragma unroll
    for (int t = 0; t < cT; ++t) {
        const floatx4 x = *(const floatx4*)(text + (size_t)t * cC + c_global);
        dot[t] = p.x * x.x + p.y * x.y + p.z * x.z + p.w * x.w;
        tsq[t] = x.x * x.x + x.y * x.y + x.z * x.z + x.w * x.w;
    }
    psq = wred(psq);
    #pragma unroll
    for (int t = 0; t < cT; ++t) { dot[t] = wred(dot[t]); tsq[t] = wred(tsq[t]); }

    __shared__ float lce[4], lcnt[4];
    if (lane == 0) {
        const float tempv = fabsf(temp[0]);
        const float pn = fmaxf(sqrtf(psq), 1e-12f);
        float sims[cT], mx = -1e30f;
        #pragma unroll
        for (int t = 0; t < cT; ++t) {
            sims[t] = dot[t] / (pn * fmaxf(sqrtf(tsq[t]), 1e-12f)) / tempv;
            mx = fmaxf(mx, sims[t]);
        }
        float se = 0.f;
        #pragma unroll
        for (int t = 0; t < cT; ++t) se += expf(sims[t] - mx);
        const float lse = logf(se);
        const int lab = labels[row];
        const int tgt = min(max(lab - 1, 0), cT - 1);
        const float ce = -(sims[tgt] - mx - lse);
        const bool valid = (lab >= 1) && (lab <= cT) && (m >= 1.0f);
        lce[wv]  = valid ? ce : 0.f;
        lcnt[wv] = valid ? 1.f : 0.f;
    }
    __syncthreads();
    if (threadIdx.x == 0) {
        bpart[blockIdx.x * 2]     = lce[0] + lce[1] + lce[2] + lce[3];
        bpart[blockIdx.x * 2 + 1] = lcnt[0] + lcnt[1] + lcnt[2] + lcnt[3];
    }
}

__global__ __launch_bounds__(256)
void loss_kernel(const float* __restrict__ bp, float* __restrict__ out) {
    const int t = threadIdx.x, lane = t & 63, w = t >> 6;
    float ce = 0.f, cnt = 0.f;
    if (t < 200) { ce = bp[t * 2]; cnt = bp[t * 2 + 1]; }
    ce = wred(ce); cnt = wred(cnt);
    __shared__ float a[8];
    if (lane == 0) { a[w * 2] = ce; a[w * 2 + 1] = cnt; }
    __syncthreads();
    if (t == 0) {
        const float s = a[0] + a[2] + a[4] + a[6];
        const float c = a[1] + a[3] + a[5] + a[7];
        out[0] = (c > 0.f) ? s / fmaxf(c, 1.f) : 0.f;
    }
}

// ---------------------------------------------------------------------------
extern "C" void kernel_launch(void* const* d_in, const int* in_sizes, int n_in,
                              void* d_out, int out_size, void* d_ws, size_t ws_size,
                              hipStream_t stream)
{
    const float* vf     = (const float*)d_in[0];
    const float* text   = (const float*)d_in[1];
    const float* masks  = (const float*)d_in[2];
    const int*   labels = (const int*)d_in[3];
    const float* temp   = (const float*)d_in[4];
    float*       outp   = (float*)d_out;

    float*    wsf   = (float*)d_ws;
    float*    bpart = wsf;                    // 200*2 floats (block partials)
    unsigned* msum  = (unsigned*)(wsf + 512); // 800 u32
    float*    part  = wsf + 4096;             // NBLK*100*16 fp32 (6.55 MB)
    const size_t PART_FLOATS = (size_t)NBLK * cN * 16;      // 1,638,400
    const size_t BITS_WORDS  = (size_t)cB * NPAD * WPB;     // 458,752
    unsigned* bits  = (unsigned*)(wsf + 4096 + PART_FLOATS);

    const bool ws_ok =
        ws_size >= (4096 + PART_FLOATS + BITS_WORDS + 64) * sizeof(float);

    bool coop_done = false;
    if (ws_ok) {
        void* args[] = { (void*)&vf, (void*)&masks, (void*)&text, (void*)&labels,
                         (void*)&temp, (void*)&bits, (void*)&msum, (void*)&part,
                         (void*)&bpart, (void*)&outp };
        hipError_t err = hipLaunchCooperativeKernel((const void*)fused_kernel,
                                                    dim3(NBLK), dim3(256),
                                                    args, 0, stream);
        coop_done = (err == hipSuccess);
    }

    if (!coop_done && ws_ok) {
        hipLaunchKernelGGL(mask_prep_kernel, dim3(cB * NPAD), dim3(256), 0, stream,
                           masks, bits, msum);
        hipLaunchKernelGGL(pool_kernel, dim3(NBLK), dim3(256), 0, stream,
                           vf, bits, part);
        hipLaunchKernelGGL(finalize_kernel, dim3(cB * cN / 4), dim3(256), 0, stream,
                           part, msum, text, labels, temp, bpart);
        hipLaunchKernelGGL(loss_kernel, dim3(1), dim3(256), 0, stream,
                           bpart, outp);
    }
}

// Round 8
// 121.359 us; speedup vs baseline: 5.4442x; 5.4442x over previous
//
#include <hip/hip_runtime.h>
#include <hip/hip_bf16.h>
#include <stdint.h>

// Problem constants (from reference setup_inputs)
constexpr int cB  = 8;
constexpr int cC  = 256;
constexpr int cHW = 128 * 128;   // 16384
constexpr int cN  = 100;
constexpr int cT  = 6;
constexpr int NPAD = 112;        // cN padded to multiple of 16
constexpr int WPB = cHW / 32;    // 512 bit-words per (b,n) row
constexpr int KSLICES = 64;      // k-slices per (b, c-tile)
constexpr int PXS = cHW / KSLICES;   // 256 px per wave
constexpr int NWIN = PXS / 32;       // 8 windows of 32 px
constexpr int NGRP = NWIN / 4;       // 2 groups of 4 windows
constexpr int NBLK = cB * 16 * (KSLICES / 4);  // 2048 blocks (4 slices/block)

typedef __attribute__((ext_vector_type(8))) short short8;
typedef __attribute__((ext_vector_type(4))) float floatx4;

// RNE fp32 pair -> packed bf16x2 (compiler emits v_cvt_pk_bf16_f32 on gfx950)
__device__ __forceinline__ unsigned pack2(float a, float b) {
    const __hip_bfloat16 ha = __float2bfloat16(a);
    const __hip_bfloat16 hb = __float2bfloat16(b);
    return (unsigned)__builtin_bit_cast(unsigned short, ha)
         | ((unsigned)__builtin_bit_cast(unsigned short, hb) << 16);
}

__device__ __forceinline__ float wred(float v) {
    #pragma unroll
    for (int off = 32; off > 0; off >>= 1) v += __shfl_xor(v, off, 64);
    return v;
}

// ---------------------------------------------------------------------------
// K0: blocks 0..895: binarize masks -> bit-pack [b][n(112)][word(512)] + msum.
//     block 896: normalize text rows -> tnorm[6][256]; zero fincnt.
// Bit order within a 32-px word: px offset o = lambda*4+c <-> bit c*8+lambda
// ---------------------------------------------------------------------------
__global__ __launch_bounds__(256)
void mask_prep_kernel(const float* __restrict__ masks, const float* __restrict__ text,
                      unsigned* __restrict__ bits, unsigned* __restrict__ msum,
                      float* __restrict__ tnorm, unsigned* __restrict__ fincnt)
{
    const int t = threadIdx.x, lane = t & 63, w = t >> 6;

    if (blockIdx.x == cB * NPAD) {       // text normalization block
        float v[cT], sq[cT];
        #pragma unroll
        for (int q = 0; q < cT; ++q) {
            v[q] = text[q * cC + t];
            sq[q] = wred(v[q] * v[q]);
        }
        __shared__ float ps[cT][4];
        if (lane == 0)
            #pragma unroll
            for (int q = 0; q < cT; ++q) ps[q][w] = sq[q];
        __syncthreads();
        #pragma unroll
        for (int q = 0; q < cT; ++q) {
            const float nrm = fmaxf(sqrtf(ps[q][0] + ps[q][1] + ps[q][2] + ps[q][3]), 1e-12f);
            tnorm[q * cC + t] = v[q] / nrm;
        }
        if (t == 0) *fincnt = 0u;
        return;
    }

    const int b = blockIdx.x / NPAD;
    const int n = blockIdx.x % NPAD;
    unsigned* dst = bits + ((size_t)b * NPAD + n) * WPB;
    if (n >= cN) { *(uint2*)(dst + t * 2) = make_uint2(0u, 0u); return; }

    const float* src = masks + ((size_t)b * cN + n) * cHW + w * 4096;
    unsigned* wdst = dst + w * 128;
    int pc = 0;
    #pragma unroll
    for (int r = 0; r < 16; ++r) {
        const floatx4 v = *(const floatx4*)(src + r * 256 + lane * 4);
        const bool b0 = v.x > 0.5f, b1 = v.y > 0.5f, b2 = v.z > 0.5f, b3 = v.w > 0.5f;
        const unsigned long long B0 = __ballot(b0), B1 = __ballot(b1),
                                 B2 = __ballot(b2), B3 = __ballot(b3);
        pc += (int)b0 + (int)b1 + (int)b2 + (int)b3;
        if (lane < 8) {
            const int sh = lane * 8;
            const unsigned word =
                  (unsigned)((B0 >> sh) & 0xFFull)
                | ((unsigned)((B1 >> sh) & 0xFFull) << 8)
                | ((unsigned)((B2 >> sh) & 0xFFull) << 16)
                | ((unsigned)((B3 >> sh) & 0xFFull) << 24);
            wdst[r * 8 + lane] = word;
        }
    }
    #pragma unroll
    for (int off = 32; off > 0; off >>= 1) pc += __shfl_xor(pc, off, 64);
    __shared__ int ps2[4];
    if (lane == 0) ps2[w] = pc;
    __syncthreads();
    if (t == 0) msum[b * cN + n] = (unsigned)(ps2[0] + ps2[1] + ps2[2] + ps2[3]);
}

// ---------------------------------------------------------------------------
// K1: pooling via MFMA. 2048 blocks x 4 waves (8 blocks/CU, 32 waves/CU).
// bid = b*256 + ct*16 + kg; wave widx does slice kg*4+widx (256 px).
// Two-pass 14KB LDS reduce -> wave 0 writes one slab [100][16] per block.
// A = mask bits (perm+umul24-expanded to bf16 0/1), B = vf fp32 -> bf16 RNE.
// ---------------------------------------------------------------------------
__global__ __launch_bounds__(256, 8)
void pool_kernel(const float* __restrict__ vf, const unsigned* __restrict__ bits,
                 float* __restrict__ part)
{
    __shared__ float red[2][28][64];     // 14,336 B

    const int tid  = threadIdx.x;
    const int lane = tid & 63;
    const int widx = tid >> 6;
    const int bid  = blockIdx.x;
    const int b    = bid >> 8;
    const int ct   = (bid >> 4) & 15;
    const int kg   = bid & 15;
    const int sl   = kg * 4 + widx;      // slice 0..63
    const int l15  = lane & 15;
    const int lk   = lane >> 4;
    const int lk2  = lk * 2;
    const int p0   = sl * PXS;

    const float* vrow = vf + ((size_t)(b * cC + ct * 16 + l15)) * cHW + p0 + lk * 8;
    const unsigned* brow = bits + ((size_t)b * NPAD + l15) * WPB + (p0 >> 5);

    floatx4 acc[7];
    #pragma unroll
    for (int mt = 0; mt < 7; ++mt) acc[mt] = (floatx4){0.f, 0.f, 0.f, 0.f};

    // B prefetch: depth 4 windows, 2 float4 each
    floatx4 vr[4][2];
    #pragma unroll
    for (int u = 0; u < 4; ++u) {
        vr[u][0] = *(const floatx4*)(vrow + u * 32);
        vr[u][1] = *(const floatx4*)(vrow + u * 32 + 4);
    }

    #pragma unroll
    for (int g = 0; g < NGRP; ++g) {
        uint4 bw[7];
        #pragma unroll
        for (int mt = 0; mt < 7; ++mt)
            bw[mt] = *(const uint4*)(brow + (size_t)mt * 16 * WPB + g * 4);
        #pragma unroll
        for (int u = 0; u < 4; ++u) {
            const int w = g * 4 + u;
            // ---- B fragment: 8 fp32 -> 8 bf16 (RNE)
            union { short8 s8; uint4 u4; } bq;
            bq.u4.x = pack2(vr[u][0].x, vr[u][0].y);
            bq.u4.y = pack2(vr[u][0].z, vr[u][0].w);
            bq.u4.z = pack2(vr[u][1].x, vr[u][1].y);
            bq.u4.w = pack2(vr[u][1].z, vr[u][1].w);
            // ---- issue B loads for window w+4
            if (g < NGRP - 1) {
                vr[u][0] = *(const floatx4*)(vrow + (w + 4) * 32);
                vr[u][1] = *(const floatx4*)(vrow + (w + 4) * 32 + 4);
            }
            // ---- A expand + MFMA per n-tile
            #pragma unroll
            for (int mt = 0; mt < 7; ++mt) {
                const unsigned word = (u == 0) ? bw[mt].x : (u == 1) ? bw[mt].y
                                    : (u == 2) ? bw[mt].z : bw[mt].w;
                // frag element j <-> bit (j&3)*8 + lk*2 + (j>>2)
                const unsigned te = (word >> lk2) & 0x01010101u;
                const unsigned to = (word >> (lk2 + 1)) & 0x01010101u;
                union { short8 s8; uint4 u4; } aq;
                aq.u4.x = __umul24(__builtin_amdgcn_perm(0u, te, 0x04010400u), 0x3F80u);
                aq.u4.y = __umul24(__builtin_amdgcn_perm(0u, te, 0x04030402u), 0x3F80u);
                aq.u4.z = __umul24(__builtin_amdgcn_perm(0u, to, 0x04010400u), 0x3F80u);
                aq.u4.w = __umul24(__builtin_amdgcn_perm(0u, to, 0x04030402u), 0x3F80u);
                acc[mt] = __builtin_amdgcn_mfma_f32_16x16x32_bf16(aq.s8, bq.s8, acc[mt], 0, 0, 0);
            }
        }
    }

    // ---- two-pass LDS reduce (14 KB): waves {0+1},{2+3} then {01+23} -> wave 0
    if (widx & 1) {                      // waves 1,3 dump
        #pragma unroll
        for (int mt = 0; mt < 7; ++mt)
            #pragma unroll
            for (int i = 0; i < 4; ++i)
                red[widx >> 1][mt * 4 + i][lane] = acc[mt][i];
    }
    __syncthreads();
    if (!(widx & 1)) {                   // waves 0,2 accumulate partner
        #pragma unroll
        for (int mt = 0; mt < 7; ++mt)
            #pragma unroll
            for (int i = 0; i < 4; ++i)
                acc[mt][i] += red[widx >> 1][mt * 4 + i][lane];
    }
    __syncthreads();
    if (widx == 2) {                     // wave 2 dumps pair-sum
        #pragma unroll
        for (int mt = 0; mt < 7; ++mt)
            #pragma unroll
            for (int i = 0; i < 4; ++i)
                red[0][mt * 4 + i][lane] = acc[mt][i];
    }
    __syncthreads();
    if (widx == 0) {                     // wave 0: final sum + slab write
        float* dst = part + (size_t)bid * (cN * 16);
        #pragma unroll
        for (int mt = 0; mt < 7; ++mt) {
            #pragma unroll
            for (int i = 0; i < 4; ++i) {
                const float s = acc[mt][i] + red[0][mt * 4 + i][lane];
                const int n = mt * 16 + lk * 4 + i;
                if (n < cN) dst[n * 16 + l15] = s;
            }
        }
    }
}

// ---------------------------------------------------------------------------
// K2: reduce partials + per (b,n) row -> normalize, sims, CE; last block
// computes the final loss (atomic counter + fences).
// grid = exactly 200 blocks x 256 threads (4 rows/block).
// ---------------------------------------------------------------------------
__global__ __launch_bounds__(256)
void finalize_kernel(const float* __restrict__ part, const unsigned* __restrict__ msum,
                     const float* __restrict__ tnorm, const int* __restrict__ labels,
                     const float* __restrict__ temp, float* __restrict__ bpart,
                     unsigned* __restrict__ fincnt, float* __restrict__ out)
{
    const int tid  = threadIdx.x;
    const int lane = tid & 63;
    const int wv   = tid >> 6;
    const int row  = blockIdx.x * 4 + wv;       // < 800 always (grid exact)
    const int b = row / cN, n = row % cN;
    const int ct  = lane >> 2;
    const int col = (lane & 3) * 4;
    const int c_global = ct * 16 + col;

    floatx4 p = (floatx4){0.f, 0.f, 0.f, 0.f};
    const float* src = part + ((size_t)(b * 256 + ct * 16)) * (cN * 16) + n * 16 + col;
    #pragma unroll
    for (int kg = 0; kg < 16; ++kg)
        p += *(const floatx4*)(src + (size_t)kg * (cN * 16));

    const float m   = (float)msum[row];
    const float inv = 1.0f / fmaxf(m, 1.0f);
    p.x *= inv; p.y *= inv; p.z *= inv; p.w *= inv;

    float psq = p.x * p.x + p.y * p.y + p.z * p.z + p.w * p.w;
    float dot[cT];
    #pragma unroll
    for (int q = 0; q < cT; ++q) {
        const floatx4 x = *(const floatx4*)(tnorm + (size_t)q * cC + c_global);
        dot[q] = p.x * x.x + p.y * x.y + p.z * x.z + p.w * x.w;
    }
    psq = wred(psq);
    #pragma unroll
    for (int q = 0; q < cT; ++q) dot[q] = wred(dot[q]);

    __shared__ float lce[4], lcnt[4];
    if (lane == 0) {
        const float tempv = fabsf(temp[0]);
        const float pn = fmaxf(sqrtf(psq), 1e-12f);
        float sims[cT], mx = -1e30f;
        #pragma unroll
        for (int q = 0; q < cT; ++q) {
            sims[q] = dot[q] / pn / tempv;
            mx = fmaxf(mx, sims[q]);
        }
        float se = 0.f;
        #pragma unroll
        for (int q = 0; q < cT; ++q) se += expf(sims[q] - mx);
        const float lse = logf(se);

        const int lab = labels[row];
        const int tgt = min(max(lab - 1, 0), cT - 1);
        const float ce = -(sims[tgt] - mx - lse);
        const bool valid = (lab >= 1) && (lab <= cT) && (m >= 1.0f);
        lce[wv]  = valid ? ce : 0.f;
        lcnt[wv] = valid ? 1.f : 0.f;
    }
    __syncthreads();
    if (tid == 0) {
        bpart[blockIdx.x * 2]     = lce[0] + lce[1] + lce[2] + lce[3];
        bpart[blockIdx.x * 2 + 1] = lcnt[0] + lcnt[1] + lcnt[2] + lcnt[3];
    }

    // ---- last block computes the loss
    __threadfence();
    __shared__ bool isLast;
    if (tid == 0)
        isLast = (__hip_atomic_fetch_add(fincnt, 1u, __ATOMIC_ACQ_REL,
                                         __HIP_MEMORY_SCOPE_AGENT) == 199u);
    __syncthreads();
    if (isLast) {
        __threadfence();
        float ce = 0.f, cnt = 0.f;
        if (tid < 200) {
            ce  = __hip_atomic_load(&bpart[tid * 2],     __ATOMIC_RELAXED, __HIP_MEMORY_SCOPE_AGENT);
            cnt = __hip_atomic_load(&bpart[tid * 2 + 1], __ATOMIC_RELAXED, __HIP_MEMORY_SCOPE_AGENT);
        }
        ce = wred(ce); cnt = wred(cnt);
        __shared__ float a[8];
        if (lane == 0) { a[wv * 2] = ce; a[wv * 2 + 1] = cnt; }
        __syncthreads();
        if (tid == 0) {
            const float s = a[0] + a[2] + a[4] + a[6];
            const float c = a[1] + a[3] + a[5] + a[7];
            out[0] = (c > 0.f) ? s / fmaxf(c, 1.f) : 0.f;
        }
    }
}

// ---------------------------------------------------------------------------
extern "C" void kernel_launch(void* const* d_in, const int* in_sizes, int n_in,
                              void* d_out, int out_size, void* d_ws, size_t ws_size,
                              hipStream_t stream)
{
    const float* vf     = (const float*)d_in[0];
    const float* text   = (const float*)d_in[1];
    const float* masks  = (const float*)d_in[2];
    const int*   labels = (const int*)d_in[3];
    const float* temp   = (const float*)d_in[4];

    float*    wsf    = (float*)d_ws;
    float*    bpart  = wsf;                       // 400 floats
    unsigned* fincnt = (unsigned*)(wsf + 408);    // 1 u32
    float*    tnorm  = wsf + 512;                 // 1536 floats
    unsigned* msum   = (unsigned*)(wsf + 2048);   // 800 u32
    float*    part   = wsf + 4096;                // NBLK*100*16 = 3,276,800 (13.1 MB)
    const size_t PART_FLOATS = (size_t)NBLK * cN * 16;
    const size_t BITS_WORDS  = (size_t)cB * NPAD * WPB;   // 458,752
    unsigned* bits   = (unsigned*)(wsf + 4096 + PART_FLOATS);

    if (ws_size < (4096 + PART_FLOATS + BITS_WORDS + 64) * sizeof(float))
        return;  // ws has always been 512 MiB; fail loudly rather than corrupt

    hipLaunchKernelGGL(mask_prep_kernel, dim3(cB * NPAD + 1), dim3(256), 0, stream,
                       masks, text, bits, msum, tnorm, fincnt);
    hipLaunchKernelGGL(pool_kernel, dim3(NBLK), dim3(256), 0, stream,
                       vf, bits, part);
    hipLaunchKernelGGL(finalize_kernel, dim3(cB * cN / 4), dim3(256), 0, stream,
                       part, msum, tnorm, labels, temp, bpart, fincnt, (float*)d_out);
}